// Round 14
// baseline (472.672 us; speedup 1.0000x reference)
//
#include <hip/hip_runtime.h>

// ---------------- constants ----------------
#define S_LEN 2048
#define NB 4
#define NH 16
#define BHN 64          // NB*NH
#define DM 1024
#define DEP 64
#define MROWS 8192      // NB*S_LEN
#define NEGB (-1.44269504e9f)

typedef __attribute__((ext_vector_type(8))) short short8;
typedef __attribute__((ext_vector_type(4))) short s16x4;
typedef __attribute__((ext_vector_type(4))) float f32x4;

#define MFMA_BF16(a, b, c) __builtin_amdgcn_mfma_f32_16x16x32_bf16((a), (b), (c), 0, 0, 0)

// K=16 bf16 MFMA (ISA §10: v_mfma_f32_16x16x16_bf16, A/B = 2 VGPRs = 4 bf16)
__device__ __forceinline__ void mfma16(const s16x4& a, const s16x4& b, f32x4& c) {
  asm("v_mfma_f32_16x16x16_bf16 %0, %1, %2, %0" : "+v"(c) : "v"(a), "v"(b));
}

typedef __attribute__((address_space(1))) const void* as1cv;
typedef __attribute__((address_space(3))) void* as3v;

__device__ __forceinline__ void gld16(const void* g, void* l) {
  // async global->LDS, 16B per lane; LDS dest = wave-uniform base + lane*16
  __builtin_amdgcn_global_load_lds((as1cv)g, (as3v)l, 16, 0, 0);
}

__device__ __forceinline__ unsigned short f2bf(float f) {
  unsigned u = __float_as_uint(f);
  u += 0x7fffu + ((u >> 16) & 1u);   // round-to-nearest-even
  return (unsigned short)(u >> 16);
}

// packed fp32x2 -> bf16x2 (RNE), 1 instruction
__device__ __forceinline__ unsigned cvtpk(float a, float b) {
  unsigned r;
  asm("v_cvt_pk_bf16_f32 %0, %1, %2" : "=v"(r) : "v"(a), "v"(b));
  return r;
}

// swizzled short-index of logical (row, 8-short granule) in a [rows][64] bf16 tile
__device__ __forceinline__ int SWZ(int row, int gran) {
  return row * 64 + ((gran ^ (row & 7)) << 3);
}

// ---------------- W transpose (z<3) + gate (z==3) ----------------
__global__ __launch_bounds__(256) void wt3_kernel(const float* __restrict__ wq,
                                                  const float* __restrict__ wk,
                                                  const float* __restrict__ wv,
                                                  unsigned short* __restrict__ WtBase,
                                                  const float* __restrict__ pf,
                                                  const float* __restrict__ wg,
                                                  const float* __restrict__ bg,
                                                  float* __restrict__ validity) {
  int z = blockIdx.z;
  if (z == 3) {
    // gate: validity[b][h] = sigmoid(pf @ wg + bg); only block (0,0,3) works
    if (blockIdx.x == 0 && blockIdx.y == 0 && threadIdx.x < 64) {
      int t = threadIdx.x;
      int b = t >> 4, h = t & 15;
      float s = bg[h];
      for (int i = 0; i < 64; i++) s += pf[b * 64 + i] * wg[i * NH + h];
      validity[t] = 1.0f / (1.0f + __expf(-s));
    }
    return;
  }
  __shared__ unsigned short T[64][72];
  const float* W = (z == 0) ? wq : (z == 1) ? wk : wv;
  unsigned short* Wt = WtBase + (size_t)z * DM * DM;
  int k0 = blockIdx.x * 64, n0 = blockIdx.y * 64;
  int t = threadIdx.x;
  int r = t >> 2, c4 = (t & 3) * 16;
  for (int j = 0; j < 16; j += 4) {
    float4 v = *(const float4*)&W[(size_t)(k0 + r) * DM + n0 + c4 + j];
    T[r][c4 + j + 0] = f2bf(v.x); T[r][c4 + j + 1] = f2bf(v.y);
    T[r][c4 + j + 2] = f2bf(v.z); T[r][c4 + j + 3] = f2bf(v.w);
  }
  __syncthreads();
  union { unsigned short us[16]; uint4 v[2]; } o;
  for (int j = 0; j < 16; j++) o.us[j] = T[c4 + j][r];
  *(uint4*)&Wt[(size_t)(n0 + r) * DM + k0 + c4] = o.v[0];
  *(uint4*)&Wt[(size_t)(n0 + r) * DM + k0 + c4 + 8] = o.v[1];
}

// ---------------- fused projection GEMM: Y_z = X_z @ W_z + b_z, z in {q,k,v} ----------------
// All z: epilogue goes through the LDS-transposed tile T[dl][sl].
// z==0,1: vectorized dwordx4 writes of head-split [BH][S][64].  z==2: writes vhT [BH][64][S].
__global__ __launch_bounds__(256) void proj3_gemm(const float* __restrict__ Xq,
                                                  const float* __restrict__ Xk,
                                                  const float* __restrict__ Xv,
                                                  const unsigned short* __restrict__ BtBase,
                                                  const float* __restrict__ bq,
                                                  const float* __restrict__ bk,
                                                  const float* __restrict__ bv,
                                                  unsigned short* __restrict__ Ybase,
                                                  unsigned short* __restrict__ vhT) {
  __shared__ union {
    struct { unsigned short As[128 * 64]; unsigned short Bs[128 * 64]; } s;
    unsigned short T[128 * 130];   // epilogue transpose tile [d][s], stride 130
  } u;
  const int K = DM;
  int z = blockIdx.z;
  const float* X = (z == 0) ? Xq : (z == 1) ? Xk : Xv;
  const float* bias = (z == 0) ? bq : (z == 1) ? bk : bv;
  const unsigned short* Bt = BtBase + (size_t)z * DM * DM;
  unsigned short* Y = Ybase + (size_t)z * MROWS * DM;
  unsigned short* As = u.s.As;
  unsigned short* Bs = u.s.Bs;

  int tid = threadIdx.x, w = tid >> 6, l = tid & 63, g = l >> 4, lc = l & 15;
  int r0 = blockIdx.x * 128, c0 = blockIdx.y * 128;
  int wr = w >> 1, wc = w & 1;
  int lrow = l >> 3, lcol = (l & 7) * 8;
  int sr = tid >> 3, sc = (tid & 7) * 8;   // A fp32 staging roles
  f32x4 acc[4][4] = {};
  for (int k0 = 0; k0 < K; k0 += 64) {
    __syncthreads();
    for (int i = 0; i < 4; i++) {
      int row = (w * 4 + i) * 8 + lrow;
      gld16(Bt + (size_t)(c0 + row) * K + k0 + lcol, &Bs[(w * 4 + i) * 512]);
    }
    for (int i = 0; i < 4; i++) {
      int row = i * 32 + sr;
      const float* src = X + (size_t)(r0 + row) * K + k0 + sc;
      float4 a0 = *(const float4*)src;
      float4 a1 = *(const float4*)(src + 4);
      uint4 o = {cvtpk(a0.x, a0.y), cvtpk(a0.z, a0.w),
                 cvtpk(a1.x, a1.y), cvtpk(a1.z, a1.w)};
      *(uint4*)&As[row * 64 + sc] = o;
    }
    __syncthreads();
    for (int kk = 0; kk < 2; kk++) {
      short8 a[4], b[4];
      for (int m = 0; m < 4; m++)
        a[m] = *(const short8*)&As[(wr * 64 + m * 16 + lc) * 64 + kk * 32 + g * 8];
      for (int n = 0; n < 4; n++)
        b[n] = *(const short8*)&Bs[(wc * 64 + n * 16 + lc) * 64 + kk * 32 + g * 8];
      for (int m = 0; m < 4; m++)
        for (int n = 0; n < 4; n++)
          acc[m][n] = MFMA_BF16(a[m], b[n], acc[m][n]);
    }
  }
  // ---- epilogue: acc -> T[d_local][s_local] (bias folded, bf16) ----
  __syncthreads();   // done reading As/Bs
  for (int n = 0; n < 4; n++) {
    int dl = wc * 64 + n * 16 + lc;           // d_local within tile
    float bi = bias[c0 + dl];
    for (int m = 0; m < 4; m++) {
      int sl = wr * 64 + m * 16 + g * 4;      // s_local base
      uint2 pk;
      pk.x = cvtpk(acc[m][n][0] + bi, acc[m][n][1] + bi);
      pk.y = cvtpk(acc[m][n][2] + bi, acc[m][n][3] + bi);
      *(uint2*)&u.T[dl * 130 + sl] = pk;      // 8B along sl, low-conflict
    }
  }
  __syncthreads();
  int b_ = r0 >> 11, s0 = r0 & 2047;          // 128-row tile stays in one b_
  if (z < 2) {
    // vectorized head-split output: per h-half a contiguous 16KB [s][d] region
    for (int hh = 0; hh < 2; hh++) {
      int c = c0 + hh * 64;
      int h = c >> 6;
      unsigned short* base = Y + (((size_t)b_ * NH + h) * S_LEN + s0) * DEP;
      for (int p = 0; p < 4; p++) {
        int flat = p * 2048 + tid * 8;        // shorts; 4x256x8 = 8192 = 128s x 64d
        int sl = flat >> 6;
        int d0 = flat & 63;                   // multiple of 8
        union { unsigned short us[8]; uint4 v; } o;
        for (int jj = 0; jj < 8; jj++)
          o.us[jj] = u.T[(hh * 64 + d0 + jj) * 130 + sl];   // stride-65-dword: no conflicts
        *(uint4*)(base + sl * DEP + d0) = o.v;
      }
    }
  } else {
    // vhT output (d-major): sl-contiguous reads, 16B stores
    int dl0 = tid >> 4, seg = tid & 15;       // 16 d x 16 s-segments
    for (int i = 0; i < 8; i++) {
      int dl = dl0 + i * 16;
      int c = c0 + dl;
      int h = c >> 6, dd = c & 63;
      unsigned short* dst =
          vhT + (((size_t)b_ * NH + h) * DEP + dd) * S_LEN + s0 + seg * 8;
      *(uint4*)dst = *(const uint4*)&u.T[dl * 130 + seg * 8];
    }
  }
}

// ---------------- fused attention (r10-best structure; Ms now fp32) ----------------
__global__ __launch_bounds__(512) void attn_fused(const unsigned short* __restrict__ qh,
                                                  const unsigned short* __restrict__ kh,
                                                  const unsigned short* __restrict__ vhT,
                                                  const float* __restrict__ validity,
                                                  const float* __restrict__ mask,
                                                  float* __restrict__ concat,
                                                  float* __restrict__ attn) {
  __shared__ unsigned short Qs[128 * 64];     // 16 KB
  __shared__ unsigned short KV[4][64 * 64];   // 32 KB: pass1 two 128-row K bufs; pass2 K[2]+V[2]
  __shared__ float Msf[S_LEN];                // 8 KB fp32 (0 or -1.44e9)

  // XCD co-location: all 16 q-tiles of a bh share one XCD slot (id % 8).
  int id = blockIdx.x;
  int cxcd = id & 7, j = id >> 3;
  int bh = cxcd * 8 + (j >> 4);
  int q0 = (j & 15) * 128;
  int b = bh >> 4, h = bh & 15;

  int tid = threadIdx.x, w = tid >> 6, l = tid & 63, g = l >> 4, lc = l & 15;
  int srow = l >> 3;                 // staging row within wave chunk (0..7)
  int sgran = (l & 7) ^ srow;        // pre-swizzled global source granule
  float scale = validity[bh] * 0.125f * 1.44269504f;   // validity/sqrt(64)*log2(e)
  for (int i = tid; i < S_LEN; i += 512)
    Msf[i] = mask[(size_t)b * S_LEN + i] * NEGB;

  const unsigned short* qb = qh + (size_t)bh * S_LEN * DEP;
  const unsigned short* kb = kh + (size_t)bh * S_LEN * DEP;
  const unsigned short* vb = vhT + (size_t)bh * DEP * S_LEN;
  int qrow = w * 16 + lc;

  // ---- stage Q (128 rows) + first 128-row K megatile (full drain) ----
  unsigned short* B0 = &KV[0][0];
  unsigned short* B1 = &KV[2][0];
  for (int i = 0; i < 2; i++)
    gld16(qb + (size_t)(q0 + i * 64 + w * 8 + srow) * DEP + sgran * 8,
          &Qs[(i * 64 + w * 8) * 64]);
  for (int i = 0; i < 2; i++)
    gld16(kb + (size_t)(i * 64 + w * 8 + srow) * DEP + sgran * 8,
          B0 + (i * 64 + w * 8) * 64);
  __syncthreads();
  short8 aq0 = *(const short8*)&Qs[SWZ(qrow, g)];      // Q-row w*16+lc, d 0..31
  short8 aq1 = *(const short8*)&Qs[SWZ(qrow, 4 + g)];  // d 32..63

  // ---- pass 1: row sums of exp (ell is per-lane scalar for q=lc) ----
  float ell = 0.f;
  for (int kt2 = 0; kt2 < 16; kt2++) {
    const int cb = kt2 & 1;
    unsigned short* cur = cb ? B1 : B0;
    if (kt2 < 15) {
      unsigned short* nxt = cb ? B0 : B1;
      for (int i = 0; i < 2; i++)
        gld16(kb + (size_t)((kt2 + 1) * 128 + i * 64 + w * 8 + srow) * DEP + sgran * 8,
              nxt + (i * 64 + w * 8) * 64);
    }
    for (int f = 0; f < 8; f++) {
      int krow = f * 16 + lc;
      short8 ak0 = *(const short8*)&cur[SWZ(krow, g)];
      short8 ak1 = *(const short8*)&cur[SWZ(krow, 4 + g)];
      f32x4 c = {};
      __builtin_amdgcn_s_setprio(1);
      c = MFMA_BF16(ak0, aq0, c);   // swapped: A=K, B=Q -> C[k-local=g*4+r][q=lc]
      c = MFMA_BF16(ak1, aq1, c);
      __builtin_amdgcn_s_setprio(0);
      f32x4 mb = *(const f32x4*)&Msf[kt2 * 128 + f * 16 + g * 4];
      ell += exp2f(fmaf(c[0], scale, mb[0])) + exp2f(fmaf(c[1], scale, mb[1])) +
             exp2f(fmaf(c[2], scale, mb[2])) + exp2f(fmaf(c[3], scale, mb[3]));
    }
    // sound: drain own prefetch BEFORE the barrier gating next iter's reads
    __builtin_amdgcn_sched_barrier(0);
    asm volatile("s_waitcnt vmcnt(0)" ::: "memory");
    __builtin_amdgcn_sched_barrier(0);
    __builtin_amdgcn_s_barrier();
  }
  ell += __shfl_xor(ell, 16, 64);
  ell += __shfl_xor(ell, 32, 64);
  float rinv = 1.0f / ell;

  // ---- pass 2 (64-row tiles; K dbuf KV[0..1], V dbuf KV[2..3]) ----
  gld16(kb + (size_t)(w * 8 + srow) * DEP + sgran * 8, &KV[0][w * 512]);
  gld16(vb + (size_t)(w * 8 + srow) * S_LEN + sgran * 8, &KV[2][w * 512]);
  __syncthreads();

  // lane owns q-row (w*16+lc); its 4 k-values per f start at col f*16+g*4
  float* arow = attn + ((size_t)bh * S_LEN + q0 + w * 16 + lc) * S_LEN + g * 4;

  f32x4 O[4] = {};
#pragma unroll 2
  for (int kt = 0; kt < 32; kt++) {
    const int cb = kt & 1;
    if (kt < 31) {
      gld16(kb + (size_t)((kt + 1) * 64 + w * 8 + srow) * DEP + sgran * 8,
            &KV[cb ^ 1][w * 512]);
      gld16(vb + (size_t)(w * 8 + srow) * S_LEN + (kt + 1) * 64 + sgran * 8,
            &KV[2 + (cb ^ 1)][w * 512]);
    }
    s16x4 pa[4];
#pragma unroll
    for (int f = 0; f < 4; f++) {
      int krow = f * 16 + lc;
      short8 ak0 = *(const short8*)&KV[cb][SWZ(krow, g)];
      short8 ak1 = *(const short8*)&KV[cb][SWZ(krow, 4 + g)];
      f32x4 c = {};
      __builtin_amdgcn_s_setprio(1);
      c = MFMA_BF16(ak0, aq0, c);
      c = MFMA_BF16(ak1, aq1, c);
      __builtin_amdgcn_s_setprio(0);
      f32x4 mb = *(const f32x4*)&Msf[kt * 64 + f * 16 + g * 4];
      float p0 = exp2f(fmaf(c[0], scale, mb[0])) * rinv;
      float p1 = exp2f(fmaf(c[1], scale, mb[1])) * rinv;
      float p2 = exp2f(fmaf(c[2], scale, mb[2])) * rinv;
      float p3 = exp2f(fmaf(c[3], scale, mb[3])) * rinv;
      *(f32x4*)(arow + kt * 64 + f * 16) = f32x4{p0, p1, p2, p3};  // direct from regs
      union { unsigned u[2]; s16x4 s; } pk;
      pk.u[0] = cvtpk(p0, p1);
      pk.u[1] = cvtpk(p2, p3);
      pa[f] = pk.s;                 // A-frag for K=16 PV: k = f*16 + g*4 + j
    }
    // PV: O[q][d] += P.V via 16x16x16 MFMAs
    __builtin_amdgcn_s_setprio(1);
#pragma unroll
    for (int f = 0; f < 4; f++) {
#pragma unroll
      for (int n = 0; n < 4; n++) {
        int vrow = n * 16 + lc;
        int gran = (f * 2 + (g >> 1)) ^ (vrow & 7);
        s16x4 bv = *(const s16x4*)&KV[2 + cb][vrow * 64 + gran * 8 + (g & 1) * 4];
        mfma16(pa[f], bv, O[n]);
      }
    }
    __builtin_amdgcn_s_setprio(0);
    // sound: drain own 2 prefetch loads (4 attn stores may stay in flight)
    __builtin_amdgcn_sched_barrier(0);
    if (kt < 31) { asm volatile("s_waitcnt vmcnt(4)" ::: "memory"); }
    __builtin_amdgcn_sched_barrier(0);
    __builtin_amdgcn_s_barrier();
  }
  for (int n = 0; n < 4; n++)
    for (int r = 0; r < 4; r++)
      concat[((size_t)b * S_LEN + q0 + w * 16 + g * 4 + r) * DM + h * DEP + n * 16 + lc] =
          O[n][r];
}

// ---------------- launch ----------------
extern "C" void kernel_launch(void* const* d_in, const int* in_sizes, int n_in,
                              void* d_out, int out_size, void* d_ws, size_t ws_size,
                              hipStream_t stream) {
  const float* q    = (const float*)d_in[0];
  const float* k    = (const float*)d_in[1];
  const float* v    = (const float*)d_in[2];
  const float* pf   = (const float*)d_in[3];
  const float* mask = (const float*)d_in[4];
  const float* wq   = (const float*)d_in[5];
  const float* bq   = (const float*)d_in[6];
  const float* wk   = (const float*)d_in[7];
  const float* bk   = (const float*)d_in[8];
  const float* wv   = (const float*)d_in[9];
  const float* bv   = (const float*)d_in[10];
  const float* wg   = (const float*)d_in[11];
  const float* bg   = (const float*)d_in[12];

  float* concat = (float*)d_out;
  float* attn   = concat + (size_t)NB * S_LEN * DM;   // 8388608 floats in

  // transient scratch inside the (not yet written) attn region of d_out:
  unsigned short* wqT = (unsigned short*)attn;       // contiguous wqT|wkT|wvT
  unsigned short* wkT = wqT + (size_t)DM * DM;
  unsigned short* wvT = wkT + (size_t)DM * DM;
  (void)wkT; (void)wvT;

  // persistent intermediates in d_ws (~67 MB):
  float* validity = (float*)d_ws;
  unsigned short* qhp = (unsigned short*)((char*)d_ws + 4096);
  unsigned short* khp = qhp + (size_t)MROWS * DM;
  unsigned short* vhp = khp + (size_t)MROWS * DM;   // slot unused (kept for layout)
  unsigned short* vhT = vhp + (size_t)MROWS * DM;

  // weight transpose (z<3) + gate (z==3) in one launch
  wt3_kernel<<<dim3(16, 16, 4), 256, 0, stream>>>(wq, wk, wv, wqT, pf, wg, bg, validity);

  proj3_gemm<<<dim3(64, 8, 3), 256, 0, stream>>>(q, k, v, wqT, bq, bk, bv, qhp, vhT);

  attn_fused<<<1024, 512, 0, stream>>>(qhp, khp, vhT, validity, mask, concat, attn);
}

// Round 15
// 440.478 us; speedup vs baseline: 1.0731x; 1.0731x over previous
//
#include <hip/hip_runtime.h>

// ---------------- constants ----------------
#define S_LEN 2048
#define NB 4
#define NH 16
#define BHN 64          // NB*NH
#define DM 1024
#define DEP 64
#define MROWS 8192      // NB*S_LEN
#define NEGB (-1.44269504e9f)

typedef __attribute__((ext_vector_type(8))) short short8;
typedef __attribute__((ext_vector_type(4))) short s16x4;
typedef __attribute__((ext_vector_type(4))) float f32x4;

#define MFMA_BF16(a, b, c) __builtin_amdgcn_mfma_f32_16x16x32_bf16((a), (b), (c), 0, 0, 0)

// K=16 bf16 MFMA (ISA §10: v_mfma_f32_16x16x16_bf16, A/B = 2 VGPRs = 4 bf16)
__device__ __forceinline__ void mfma16(const s16x4& a, const s16x4& b, f32x4& c) {
  asm("v_mfma_f32_16x16x16_bf16 %0, %1, %2, %0" : "+v"(c) : "v"(a), "v"(b));
}

typedef __attribute__((address_space(1))) const void* as1cv;
typedef __attribute__((address_space(3))) void* as3v;

__device__ __forceinline__ void gld16(const void* g, void* l) {
  // async global->LDS, 16B per lane; LDS dest = wave-uniform base + lane*16
  __builtin_amdgcn_global_load_lds((as1cv)g, (as3v)l, 16, 0, 0);
}

__device__ __forceinline__ unsigned short f2bf(float f) {
  unsigned u = __float_as_uint(f);
  u += 0x7fffu + ((u >> 16) & 1u);   // round-to-nearest-even
  return (unsigned short)(u >> 16);
}

// packed fp32x2 -> bf16x2 (RNE), 1 instruction
__device__ __forceinline__ unsigned cvtpk(float a, float b) {
  unsigned r;
  asm("v_cvt_pk_bf16_f32 %0, %1, %2" : "=v"(r) : "v"(a), "v"(b));
  return r;
}

// swizzled short-index of logical (row, 8-short granule) in a [rows][64] bf16 tile
__device__ __forceinline__ int SWZ(int row, int gran) {
  return row * 64 + ((gran ^ (row & 7)) << 3);
}

// ---------------- W transpose (z<3) + gate (z==3) ----------------
__global__ __launch_bounds__(256) void wt3_kernel(const float* __restrict__ wq,
                                                  const float* __restrict__ wk,
                                                  const float* __restrict__ wv,
                                                  unsigned short* __restrict__ WtBase,
                                                  const float* __restrict__ pf,
                                                  const float* __restrict__ wg,
                                                  const float* __restrict__ bg,
                                                  float* __restrict__ validity) {
  int z = blockIdx.z;
  if (z == 3) {
    if (blockIdx.x == 0 && blockIdx.y == 0 && threadIdx.x < 64) {
      int t = threadIdx.x;
      int b = t >> 4, h = t & 15;
      float s = bg[h];
      for (int i = 0; i < 64; i++) s += pf[b * 64 + i] * wg[i * NH + h];
      validity[t] = 1.0f / (1.0f + __expf(-s));
    }
    return;
  }
  __shared__ unsigned short T[64][72];
  const float* W = (z == 0) ? wq : (z == 1) ? wk : wv;
  unsigned short* Wt = WtBase + (size_t)z * DM * DM;
  int k0 = blockIdx.x * 64, n0 = blockIdx.y * 64;
  int t = threadIdx.x;
  int r = t >> 2, c4 = (t & 3) * 16;
  for (int j = 0; j < 16; j += 4) {
    float4 v = *(const float4*)&W[(size_t)(k0 + r) * DM + n0 + c4 + j];
    T[r][c4 + j + 0] = f2bf(v.x); T[r][c4 + j + 1] = f2bf(v.y);
    T[r][c4 + j + 2] = f2bf(v.z); T[r][c4 + j + 3] = f2bf(v.w);
  }
  __syncthreads();
  union { unsigned short us[16]; uint4 v[2]; } o;
  for (int j = 0; j < 16; j++) o.us[j] = T[c4 + j][r];
  *(uint4*)&Wt[(size_t)(n0 + r) * DM + k0 + c4] = o.v[0];
  *(uint4*)&Wt[(size_t)(n0 + r) * DM + k0 + c4 + 8] = o.v[1];
}

// ---------------- fused projection GEMM: Y_z = X_z @ W_z + b_z, z in {q,k,v} ----------------
// z==0,1: direct head-split stores (proven r13 path). z==2: LDS-transposed vhT epilogue.
__global__ __launch_bounds__(256) void proj3_gemm(const float* __restrict__ Xq,
                                                  const float* __restrict__ Xk,
                                                  const float* __restrict__ Xv,
                                                  const unsigned short* __restrict__ BtBase,
                                                  const float* __restrict__ bq,
                                                  const float* __restrict__ bk,
                                                  const float* __restrict__ bv,
                                                  unsigned short* __restrict__ Ybase,
                                                  unsigned short* __restrict__ vhT) {
  __shared__ union {
    struct { unsigned short As[128 * 64]; unsigned short Bs[128 * 64]; } s;
    unsigned short T[128 * 130];   // z==2 epilogue transpose tile [d][s], stride 130
  } u;
  const int K = DM;
  int z = blockIdx.z;
  const float* X = (z == 0) ? Xq : (z == 1) ? Xk : Xv;
  const float* bias = (z == 0) ? bq : (z == 1) ? bk : bv;
  const unsigned short* Bt = BtBase + (size_t)z * DM * DM;
  unsigned short* Y = Ybase + (size_t)z * MROWS * DM;
  unsigned short* As = u.s.As;
  unsigned short* Bs = u.s.Bs;

  int tid = threadIdx.x, w = tid >> 6, l = tid & 63, g = l >> 4, lc = l & 15;
  int r0 = blockIdx.x * 128, c0 = blockIdx.y * 128;
  int wr = w >> 1, wc = w & 1;
  int lrow = l >> 3, lcol = (l & 7) * 8;
  int sr = tid >> 3, sc = (tid & 7) * 8;   // A fp32 staging roles
  f32x4 acc[4][4] = {};
  for (int k0 = 0; k0 < K; k0 += 64) {
    __syncthreads();
    for (int i = 0; i < 4; i++) {
      int row = (w * 4 + i) * 8 + lrow;
      gld16(Bt + (size_t)(c0 + row) * K + k0 + lcol, &Bs[(w * 4 + i) * 512]);
    }
    for (int i = 0; i < 4; i++) {
      int row = i * 32 + sr;
      const float* src = X + (size_t)(r0 + row) * K + k0 + sc;
      float4 a0 = *(const float4*)src;
      float4 a1 = *(const float4*)(src + 4);
      uint4 o = {cvtpk(a0.x, a0.y), cvtpk(a0.z, a0.w),
                 cvtpk(a1.x, a1.y), cvtpk(a1.z, a1.w)};
      *(uint4*)&As[row * 64 + sc] = o;
    }
    __syncthreads();
    for (int kk = 0; kk < 2; kk++) {
      short8 a[4], b[4];
      for (int m = 0; m < 4; m++)
        a[m] = *(const short8*)&As[(wr * 64 + m * 16 + lc) * 64 + kk * 32 + g * 8];
      for (int n = 0; n < 4; n++)
        b[n] = *(const short8*)&Bs[(wc * 64 + n * 16 + lc) * 64 + kk * 32 + g * 8];
      for (int m = 0; m < 4; m++)
        for (int n = 0; n < 4; n++)
          acc[m][n] = MFMA_BF16(a[m], b[n], acc[m][n]);
    }
  }
  if (z < 2) {
    for (int n = 0; n < 4; n++) {
      int c = c0 + wc * 64 + n * 16 + lc;
      float bi = bias[c];
      int h = c >> 6, d = c & 63;
      for (int m = 0; m < 4; m++) {
        int rowbase = r0 + wr * 64 + m * 16 + g * 4;
        for (int r = 0; r < 4; r++) {
          int row = rowbase + r;
          int b_ = row >> 11, s = row & 2047;
          Y[(((size_t)b_ * NH + h) * S_LEN + s) * DEP + d] = f2bf(acc[m][n][r] + bi);
        }
      }
    }
  } else {
    // ---- transposed epilogue: acc -> T[d_local][s_local] -> vhT[bh][d][s] ----
    __syncthreads();   // done reading As/Bs
    for (int n = 0; n < 4; n++) {
      int dl = wc * 64 + n * 16 + lc;           // d_local within tile
      float bi = bias[c0 + dl];
      for (int m = 0; m < 4; m++) {
        int sl = wr * 64 + m * 16 + g * 4;      // s_local base
        uint2 pk;
        pk.x = cvtpk(acc[m][n][0] + bi, acc[m][n][1] + bi);
        pk.y = cvtpk(acc[m][n][2] + bi, acc[m][n][3] + bi);
        *(uint2*)&u.T[dl * 130 + sl] = pk;      // 8B, ~4-way conflict max
      }
    }
    __syncthreads();
    int b_ = r0 >> 11, s0 = r0 & 2047;          // 128-row tile stays in one b_
    int dl0 = tid >> 4, seg = tid & 15;         // 16 d x 16 s-segments
    for (int i = 0; i < 8; i++) {
      int dl = dl0 + i * 16;
      int c = c0 + dl;
      int h = c >> 6, dd = c & 63;
      unsigned short* dst =
          vhT + (((size_t)b_ * NH + h) * DEP + dd) * S_LEN + s0 + seg * 8;
      *(uint4*)dst = *(const uint4*)&u.T[dl * 130 + seg * 8];
    }
  }
}

// ---------------- fused attention (r10-best structure, bf16 MsB) ----------------
__global__ __launch_bounds__(512) void attn_fused(const unsigned short* __restrict__ qh,
                                                  const unsigned short* __restrict__ kh,
                                                  const unsigned short* __restrict__ vhT,
                                                  const float* __restrict__ validity,
                                                  const float* __restrict__ mask,
                                                  float* __restrict__ concat,
                                                  float* __restrict__ attn) {
  __shared__ unsigned short Qs[128 * 64];     // 16 KB
  __shared__ unsigned short KV[4][64 * 64];   // 32 KB: pass1 two 128-row K bufs; pass2 K[2]+V[2]
  __shared__ unsigned short MsB[S_LEN];       // 4 KB bf16 (values: 0 or -1.44e9, exact)

  // XCD co-location: all 16 q-tiles of a bh share one XCD slot (id % 8).
  int id = blockIdx.x;
  int cxcd = id & 7, j = id >> 3;
  int bh = cxcd * 8 + (j >> 4);
  int q0 = (j & 15) * 128;
  int b = bh >> 4, h = bh & 15;

  int tid = threadIdx.x, w = tid >> 6, l = tid & 63, g = l >> 4, lc = l & 15;
  int srow = l >> 3;                 // staging row within wave chunk (0..7)
  int sgran = (l & 7) ^ srow;        // pre-swizzled global source granule
  float scale = validity[bh] * 0.125f * 1.44269504f;   // validity/sqrt(64)*log2(e)
  for (int i = tid; i < S_LEN; i += 512)
    MsB[i] = f2bf(mask[(size_t)b * S_LEN + i] * NEGB);

  const unsigned short* qb = qh + (size_t)bh * S_LEN * DEP;
  const unsigned short* kb = kh + (size_t)bh * S_LEN * DEP;
  const unsigned short* vb = vhT + (size_t)bh * DEP * S_LEN;
  int qrow = w * 16 + lc;

  // ---- stage Q (128 rows) + first 128-row K megatile (full drain) ----
  unsigned short* B0 = &KV[0][0];
  unsigned short* B1 = &KV[2][0];
  for (int i = 0; i < 2; i++)
    gld16(qb + (size_t)(q0 + i * 64 + w * 8 + srow) * DEP + sgran * 8,
          &Qs[(i * 64 + w * 8) * 64]);
  for (int i = 0; i < 2; i++)
    gld16(kb + (size_t)(i * 64 + w * 8 + srow) * DEP + sgran * 8,
          B0 + (i * 64 + w * 8) * 64);
  __syncthreads();
  short8 aq0 = *(const short8*)&Qs[SWZ(qrow, g)];      // Q-row w*16+lc, d 0..31
  short8 aq1 = *(const short8*)&Qs[SWZ(qrow, 4 + g)];  // d 32..63

  // ---- pass 1: row sums of exp (ell is per-lane scalar for q=lc) ----
  float ell = 0.f;
  for (int kt2 = 0; kt2 < 16; kt2++) {
    const int cb = kt2 & 1;
    unsigned short* cur = cb ? B1 : B0;
    if (kt2 < 15) {
      unsigned short* nxt = cb ? B0 : B1;
      for (int i = 0; i < 2; i++)
        gld16(kb + (size_t)((kt2 + 1) * 128 + i * 64 + w * 8 + srow) * DEP + sgran * 8,
              nxt + (i * 64 + w * 8) * 64);
    }
    for (int f = 0; f < 8; f++) {
      int krow = f * 16 + lc;
      short8 ak0 = *(const short8*)&cur[SWZ(krow, g)];
      short8 ak1 = *(const short8*)&cur[SWZ(krow, 4 + g)];
      f32x4 c = {};
      __builtin_amdgcn_s_setprio(1);
      c = MFMA_BF16(ak0, aq0, c);   // swapped: A=K, B=Q -> C[k-local=g*4+r][q=lc]
      c = MFMA_BF16(ak1, aq1, c);
      __builtin_amdgcn_s_setprio(0);
      uint2 mu = *(const uint2*)&MsB[kt2 * 128 + f * 16 + g * 4];
      float mb0 = __uint_as_float(mu.x << 16);
      float mb1 = __uint_as_float(mu.x & 0xFFFF0000u);
      float mb2 = __uint_as_float(mu.y << 16);
      float mb3 = __uint_as_float(mu.y & 0xFFFF0000u);
      ell += exp2f(fmaf(c[0], scale, mb0)) + exp2f(fmaf(c[1], scale, mb1)) +
             exp2f(fmaf(c[2], scale, mb2)) + exp2f(fmaf(c[3], scale, mb3));
    }
    // sound: drain own prefetch BEFORE the barrier gating next iter's reads
    __builtin_amdgcn_sched_barrier(0);
    asm volatile("s_waitcnt vmcnt(0)" ::: "memory");
    __builtin_amdgcn_sched_barrier(0);
    __builtin_amdgcn_s_barrier();
  }
  ell += __shfl_xor(ell, 16, 64);
  ell += __shfl_xor(ell, 32, 64);
  float rinv = 1.0f / ell;

  // ---- pass 2 (64-row tiles; K dbuf KV[0..1], V dbuf KV[2..3]) ----
  gld16(kb + (size_t)(w * 8 + srow) * DEP + sgran * 8, &KV[0][w * 512]);
  gld16(vb + (size_t)(w * 8 + srow) * S_LEN + sgran * 8, &KV[2][w * 512]);
  __syncthreads();

  // lane owns q-row (w*16+lc); its 4 k-values per f start at col f*16+g*4
  float* arow = attn + ((size_t)bh * S_LEN + q0 + w * 16 + lc) * S_LEN + g * 4;

  f32x4 O[4] = {};
#pragma unroll 2
  for (int kt = 0; kt < 32; kt++) {
    const int cb = kt & 1;
    if (kt < 31) {
      gld16(kb + (size_t)((kt + 1) * 64 + w * 8 + srow) * DEP + sgran * 8,
            &KV[cb ^ 1][w * 512]);
      gld16(vb + (size_t)(w * 8 + srow) * S_LEN + (kt + 1) * 64 + sgran * 8,
            &KV[2 + (cb ^ 1)][w * 512]);
    }
    s16x4 pa[4];
#pragma unroll
    for (int f = 0; f < 4; f++) {
      int krow = f * 16 + lc;
      short8 ak0 = *(const short8*)&KV[cb][SWZ(krow, g)];
      short8 ak1 = *(const short8*)&KV[cb][SWZ(krow, 4 + g)];
      f32x4 c = {};
      __builtin_amdgcn_s_setprio(1);
      c = MFMA_BF16(ak0, aq0, c);
      c = MFMA_BF16(ak1, aq1, c);
      __builtin_amdgcn_s_setprio(0);
      uint2 mu = *(const uint2*)&MsB[kt * 64 + f * 16 + g * 4];
      float mb0 = __uint_as_float(mu.x << 16);
      float mb1 = __uint_as_float(mu.x & 0xFFFF0000u);
      float mb2 = __uint_as_float(mu.y << 16);
      float mb3 = __uint_as_float(mu.y & 0xFFFF0000u);
      float p0 = exp2f(fmaf(c[0], scale, mb0)) * rinv;
      float p1 = exp2f(fmaf(c[1], scale, mb1)) * rinv;
      float p2 = exp2f(fmaf(c[2], scale, mb2)) * rinv;
      float p3 = exp2f(fmaf(c[3], scale, mb3)) * rinv;
      *(f32x4*)(arow + kt * 64 + f * 16) = f32x4{p0, p1, p2, p3};  // direct from regs
      union { unsigned u[2]; s16x4 s; } pk;
      pk.u[0] = cvtpk(p0, p1);
      pk.u[1] = cvtpk(p2, p3);
      pa[f] = pk.s;                 // A-frag for K=16 PV: k = f*16 + g*4 + j
    }
    // PV: O[q][d] += P.V via 16x16x16 MFMAs
    __builtin_amdgcn_s_setprio(1);
#pragma unroll
    for (int f = 0; f < 4; f++) {
#pragma unroll
      for (int n = 0; n < 4; n++) {
        int vrow = n * 16 + lc;
        int gran = (f * 2 + (g >> 1)) ^ (vrow & 7);
        s16x4 bv = *(const s16x4*)&KV[2 + cb][vrow * 64 + gran * 8 + (g & 1) * 4];
        mfma16(pa[f], bv, O[n]);
      }
    }
    __builtin_amdgcn_s_setprio(0);
    // sound: drain own 2 prefetch loads (4 attn stores may stay in flight)
    __builtin_amdgcn_sched_barrier(0);
    if (kt < 31) { asm volatile("s_waitcnt vmcnt(4)" ::: "memory"); }
    __builtin_amdgcn_sched_barrier(0);
    __builtin_amdgcn_s_barrier();
  }
  for (int n = 0; n < 4; n++)
    for (int r = 0; r < 4; r++)
      concat[((size_t)b * S_LEN + q0 + w * 16 + g * 4 + r) * DM + h * DEP + n * 16 + lc] =
          O[n][r];
}

// ---------------- launch ----------------
extern "C" void kernel_launch(void* const* d_in, const int* in_sizes, int n_in,
                              void* d_out, int out_size, void* d_ws, size_t ws_size,
                              hipStream_t stream) {
  const float* q    = (const float*)d_in[0];
  const float* k    = (const float*)d_in[1];
  const float* v    = (const float*)d_in[2];
  const float* pf   = (const float*)d_in[3];
  const float* mask = (const float*)d_in[4];
  const float* wq   = (const float*)d_in[5];
  const float* bq   = (const float*)d_in[6];
  const float* wk   = (const float*)d_in[7];
  const float* bk   = (const float*)d_in[8];
  const float* wv   = (const float*)d_in[9];
  const float* bv   = (const float*)d_in[10];
  const float* wg   = (const float*)d_in[11];
  const float* bg   = (const float*)d_in[12];

  float* concat = (float*)d_out;
  float* attn   = concat + (size_t)NB * S_LEN * DM;   // 8388608 floats in

  // transient scratch inside the (not yet written) attn region of d_out:
  unsigned short* wqT = (unsigned short*)attn;       // contiguous wqT|wkT|wvT

  // persistent intermediates in d_ws (~67 MB):
  float* validity = (float*)d_ws;
  unsigned short* qhp = (unsigned short*)((char*)d_ws + 4096);
  unsigned short* khp = qhp + (size_t)MROWS * DM;
  unsigned short* vhp = khp + (size_t)MROWS * DM;   // slot unused (kept for layout)
  unsigned short* vhT = vhp + (size_t)MROWS * DM;
  (void)khp;

  // weight transpose (z<3) + gate (z==3) in one launch
  wt3_kernel<<<dim3(16, 16, 4), 256, 0, stream>>>(wq, wk, wv, wqT, pf, wg, bg, validity);

  proj3_gemm<<<dim3(64, 8, 3), 256, 0, stream>>>(q, k, v, wqT, bq, bk, bv, qhp, vhT);

  attn_fused<<<1024, 512, 0, stream>>>(qhp, khp, vhT, validity, mask, concat, attn);
}